// Round 8
// baseline (663.180 us; speedup 1.0000x reference)
//
#include <hip/hip_runtime.h>
#include <math.h>

#define B_ 64
#define N_ 16384
#define K_ 8
#define SCALE 0.125f          // 1/sqrt(64)
#define LN_EPS 1e-5f
#define CHUNKS 16
#define REC 528               // record: 512 Y + 8 S + 8 t1

__device__ __forceinline__ float wsum64(float v) {
#pragma unroll
  for (int m = 1; m < 64; m <<= 1) v += __shfl_xor(v, m);
  return v;
}

// slots = mu + sigma * noise   (32768 elems)
__global__ void init_slots(const float* __restrict__ noise, const float* __restrict__ mu,
                           const float* __restrict__ sg, float* __restrict__ slots) {
  int i = blockIdx.x * blockDim.x + threadIdx.x;
  int d = i & 63;
  slots[i] = mu[d] + sg[d] * noise[i];
}

// Per (b,kk): q = LN(slots; ln_slots)@wq + bq ; fold through wk and input-LN affine.
__global__ __launch_bounds__(64) void prep_q(
    const float* __restrict__ slots,
    const float* __restrict__ lnsw, const float* __restrict__ lnsb,
    const float* __restrict__ wq, const float* __restrict__ bq,
    const float* __restrict__ wk, const float* __restrict__ bk,
    const float* __restrict__ lniw, const float* __restrict__ lnib,
    float* __restrict__ qprep) {
  const int bk_i = blockIdx.x;            // b*8+kk
  const int b = bk_i >> 3, kk = bk_i & 7;
  const int d = threadIdx.x;
  __shared__ float xs[64], qsh[64], wkl[64 * 65];
  for (int i = 0; i < 64; ++i) wkl[i * 65 + d] = wk[i * 64 + d];
  float s = slots[bk_i * 64 + d];
  float m = wsum64(s) * (1.f / 64.f);
  float df = s - m;
  float var = wsum64(df * df) * (1.f / 64.f);
  float r = 1.f / sqrtf(var + LN_EPS);
  xs[d] = df * r * lnsw[d] + lnsb[d];
  __syncthreads();
  float q = bq[d];
  for (int c = 0; c < 64; ++c) q += xs[c] * wq[c * 64 + d];
  qsh[d] = q;
  __syncthreads();
  float qp = 0.f, c0 = 0.f;
  for (int dd = 0; dd < 64; ++dd) {
    float qd = qsh[dd];
    qp += wkl[d * 65 + dd] * qd;
    c0 += qd * bk[dd];
  }
  float qw = qp * lniw[d] * SCALE;
  float As = wsum64(qw);
  float Bp = wsum64(qp * lnib[d]);
  float Bc = (Bp + c0) * SCALE;
  float* rec = qprep + b * REC;
  rec[d * 8 + kk] = qw;                   // qwT[c][kk]
  if (d == 0) { rec[512 + kk] = As; rec[520 + kk] = Bc; }
}

// Streaming pass: grid = B*16 = 1024 blocks x 256 threads, 2 blocks/CU (8 waves).
// Coalesced float4 loads (every cache line fetched once) -> registers ->
// XOR-swizzled f32 LDS microtile (wave-private, no block barriers in loop).
// Phase A reads rows (uniform banks via swizzle), qw via scalar cache.
// Phase B reads quads back with the same swizzle. Register prefetch of the
// next microtile is issued right after the LDS writes, hidden under compute.
__global__ __launch_bounds__(256, 2) void attn_pass(
    const float* __restrict__ inp, const float* __restrict__ qprep,
    float* __restrict__ part) {
  __shared__ __align__(16) float xls[4][64 * 64];   // 64 KB: 4 waves x 64-row f32 tile
  __shared__ __align__(16) float awl[4][64 * 12];   // 12 KB: a*r per row (stride 12)
  __shared__ float redST[64];
  const int tid = threadIdx.x;
  const int w = tid >> 6, lane = tid & 63;
  const int b = blockIdx.x >> 4, chunk = blockIdx.x & 15;
  const float* __restrict__ qp = qprep + b * REC;   // wave-uniform -> s_load
  const float* srcw = inp + ((size_t)b * N_ + (size_t)(chunk * 1024 + w * 256)) * 64;
  float As_[8], Bc_[8];
#pragma unroll
  for (int kq = 0; kq < 8; ++kq) { As_[kq] = qp[512 + kq]; Bc_[kq] = qp[520 + kq]; }
  float* __restrict__ xw = xls[w];
  float* __restrict__ aww = awl[w];
  const int g = lane >> 4, c = lane & 15;           // load / phase-B mapping
  const int cl = c & 7, ch = c & 8;
  float Y[8][4];
  float sS[8], sT[8];
#pragma unroll
  for (int kq = 0; kq < 8; ++kq) {
    sS[kq] = 0.f; sT[kq] = 0.f;
#pragma unroll
    for (int e = 0; e < 4; ++e) Y[kq][e] = 0.f;
  }
  // prologue: coalesced load of microtile 0 (lane (g,c) <- row 4i+g, quad c)
  float4 xr[16];
#pragma unroll
  for (int i = 0; i < 16; ++i)
    xr[i] = *reinterpret_cast<const float4*>(srcw + (size_t)(4 * i + g) * 64 + c * 4);
  for (int mt = 0; mt < 4; ++mt) {
    // ---- stage regs -> LDS, XOR-swizzled quads ----
#pragma unroll
    for (int i = 0; i < 16; ++i) {
      const int row = 4 * i + g;
      const int phys = ch | (cl ^ (row & 7));
      *reinterpret_cast<float4*>(&xw[row * 64 + phys * 4]) = xr[i];
    }
    // ---- prefetch next microtile into the freed registers ----
    if (mt < 3) {
#pragma unroll
      for (int i = 0; i < 16; ++i)
        xr[i] = *reinterpret_cast<const float4*>(
            srcw + (size_t)((mt + 1) * 64 + 4 * i + g) * 64 + c * 4);
    }
    // ---- phase A: full row per lane (row = lane), qw from scalar cache ----
    float sum = 0.f, sq = 0.f;
    float l[8] = {0, 0, 0, 0, 0, 0, 0, 0};
#pragma unroll
    for (int j = 0; j < 16; ++j) {
      const int phys = (j & 8) | ((j & 7) ^ (lane & 7));
      const float4 xv = *reinterpret_cast<const float4*>(&xw[lane * 64 + phys * 4]);
      const float xc[4] = {xv.x, xv.y, xv.z, xv.w};
#pragma unroll
      for (int e = 0; e < 4; ++e) {
        const int cc = j * 4 + e;
        const float v = xc[e];
        sum += v; sq += v * v;
#pragma unroll
        for (int kq = 0; kq < 8; ++kq) l[kq] += qp[cc * 8 + kq] * v;
      }
    }
    const float m = sum * (1.f / 64.f);
    const float var = sq * (1.f / 64.f) - m * m;
    const float rs = 1.f / sqrtf(var + LN_EPS);
    const float mr = m * rs;
    float lmax = -1e30f;
#pragma unroll
    for (int kq = 0; kq < 8; ++kq) {
      l[kq] = rs * l[kq] - mr * As_[kq] + Bc_[kq];
      lmax = fmaxf(lmax, l[kq]);
    }
    float es = 0.f;
#pragma unroll
    for (int kq = 0; kq < 8; ++kq) { l[kq] = __expf(l[kq] - lmax); es += l[kq]; }
    const float inv = 1.f / es;
#pragma unroll
    for (int kq = 0; kq < 8; ++kq) {
      const float a = l[kq] * inv;
      sS[kq] += a;
      sT[kq] += a * mr;
      l[kq] = a * rs;                    // a*r for the Y accumulation
    }
    *reinterpret_cast<float4*>(&aww[lane * 12])     = make_float4(l[0], l[1], l[2], l[3]);
    *reinterpret_cast<float4*>(&aww[lane * 12 + 4]) = make_float4(l[4], l[5], l[6], l[7]);
    // ---- phase B: lane (g,c): rows 4t+g, its quad c; a broadcast per row ----
#pragma unroll
    for (int t = 0; t < 16; ++t) {
      const int row = 4 * t + g;
      const float4 a0 = *reinterpret_cast<const float4*>(&aww[row * 12]);
      const float4 a1 = *reinterpret_cast<const float4*>(&aww[row * 12 + 4]);
      const int phys = ch | (cl ^ (row & 7));
      const float4 xv = *reinterpret_cast<const float4*>(&xw[row * 64 + phys * 4]);
      const float xc[4] = {xv.x, xv.y, xv.z, xv.w};
      const float aa[8] = {a0.x, a0.y, a0.z, a0.w, a1.x, a1.y, a1.z, a1.w};
#pragma unroll
      for (int kq = 0; kq < 8; ++kq)
#pragma unroll
        for (int e = 0; e < 4; ++e) Y[kq][e] += aa[kq] * xc[e];
    }
  }
  // ---- epilogue ----
#pragma unroll
  for (int kq = 0; kq < 8; ++kq) { sS[kq] = wsum64(sS[kq]); sT[kq] = wsum64(sT[kq]); }
  if (lane == 0) {
#pragma unroll
    for (int i = 0; i < 8; ++i) { redST[w * 16 + i] = sS[i]; redST[w * 16 + 8 + i] = sT[i]; }
  }
  // reduce Y over the 4 g-groups (lanes xor 16, 32)
#pragma unroll
  for (int kq = 0; kq < 8; ++kq)
#pragma unroll
    for (int e = 0; e < 4; ++e) {
      Y[kq][e] += __shfl_xor(Y[kq][e], 16);
      Y[kq][e] += __shfl_xor(Y[kq][e], 32);
    }
  if (lane < 16) {     // lanes 0..15 hold quad c = lane
#pragma unroll
    for (int kq = 0; kq < 8; ++kq)
      *reinterpret_cast<float4*>(&aww[kq * 64 + lane * 4]) =
          make_float4(Y[kq][0], Y[kq][1], Y[kq][2], Y[kq][3]);
  }
  __syncthreads();
  float* dst = part + (size_t)blockIdx.x * REC;
  for (int o = tid; o < 512; o += 256)
    dst[o] = awl[0][o] + awl[1][o] + awl[2][o] + awl[3][o];
  if (tid < 16)
    dst[512 + tid] = redST[tid] + redST[16 + tid] + redST[32 + tid] + redST[48 + tid];
}

// Fused: partial-reduce -> updates -> GRU -> LN -> MLP -> new slots -> q-prep(next).
__global__ __launch_bounds__(256) void slot_update(
    const float* __restrict__ part, const float* slots_in,
    const float* __restrict__ lniw, const float* __restrict__ lnib,
    const float* __restrict__ wv, const float* __restrict__ bv,
    const float* __restrict__ wih, const float* __restrict__ bih,
    const float* __restrict__ whh, const float* __restrict__ bhh,
    const float* __restrict__ lnfw, const float* __restrict__ lnfb,
    const float* __restrict__ w1, const float* __restrict__ b1,
    const float* __restrict__ w2, const float* __restrict__ b2,
    const float* __restrict__ lnsw, const float* __restrict__ lnsb,
    const float* __restrict__ wq, const float* __restrict__ bq,
    const float* __restrict__ wk, const float* __restrict__ bkv,
    float* slots_out, float* __restrict__ qprep, const int do_prep) {
  const int bk_i = blockIdx.x, b = bk_i >> 3, kk = bk_i & 7;
  const int tid = threadIdx.x, cq = tid >> 6, d = tid & 63;
  const int c0 = cq * 16;
  __shared__ float pA[4][68], pB[4][68], pC[4][68], pD[4][68];
  __shared__ float xsh[64], psh[64], ush[64], hsh[64], snsh[64], qsh[64];
  __shared__ float hid1[2][132];
  const float* pb = part + (size_t)(b * CHUNKS) * REC;
  float S = 0.f, T1 = 0.f;
#pragma unroll
  for (int ch = 0; ch < CHUNKS; ++ch) {
    S += pb[ch * REC + 512 + kk];
    T1 += pb[ch * REC + 520 + kk];
  }
  {
    float y = 0.f;
#pragma unroll
    for (int cc = 0; cc < 4; ++cc)
      y += pb[(size_t)(cq * 4 + cc) * REC + kk * 64 + d];
    pA[cq][d] = y;
  }
  const float prev = slots_in[bk_i * 64 + d];
  if (cq == 0) psh[d] = prev;
  __syncthreads();                               // s1
  if (cq == 0) {
    const float Y = pA[0][d] + pA[1][d] + pA[2][d] + pA[3][d];
    xsh[d] = lniw[d] * (Y - T1) + lnib[d] * S;
  }
  __syncthreads();                               // s2
  {
    float up = 0.f, h0 = 0.f, h1 = 0.f, h2 = 0.f;
    for (int c = c0; c < c0 + 16; ++c) {
      const float xc = xsh[c], pc = psh[c];
      up += wv[c * 64 + d] * xc;
      h0 += pc * whh[c * 192 + d];
      h1 += pc * whh[c * 192 + 64 + d];
      h2 += pc * whh[c * 192 + 128 + d];
    }
    pA[cq][d] = up; pB[cq][d] = h0; pC[cq][d] = h1; pD[cq][d] = h2;
  }
  __syncthreads();                               // s3
  float hh0 = 0.f, hh1 = 0.f, hh2 = 0.f;
  if (cq == 0) {
    ush[d] = S * bv[d] + pA[0][d] + pA[1][d] + pA[2][d] + pA[3][d];
    hh0 = bhh[d] + pB[0][d] + pB[1][d] + pB[2][d] + pB[3][d];
    hh1 = bhh[64 + d] + pC[0][d] + pC[1][d] + pC[2][d] + pC[3][d];
    hh2 = bhh[128 + d] + pD[0][d] + pD[1][d] + pD[2][d] + pD[3][d];
  }
  __syncthreads();                               // s4
  {
    float g0 = 0.f, g1 = 0.f, g2 = 0.f;
    for (int c = c0; c < c0 + 16; ++c) {
      const float uc = ush[c];
      g0 += uc * wih[c * 192 + d];
      g1 += uc * wih[c * 192 + 64 + d];
      g2 += uc * wih[c * 192 + 128 + d];
    }
    pA[cq][d] = g0; pB[cq][d] = g1; pC[cq][d] = g2;
  }
  __syncthreads();                               // s5
  if (cq == 0) {
    const float gi0 = bih[d] + pA[0][d] + pA[1][d] + pA[2][d] + pA[3][d];
    const float gi1 = bih[64 + d] + pB[0][d] + pB[1][d] + pB[2][d] + pB[3][d];
    const float gi2 = bih[128 + d] + pC[0][d] + pC[1][d] + pC[2][d] + pC[3][d];
    const float rg = 1.f / (1.f + __expf(-(gi0 + hh0)));
    const float zg = 1.f / (1.f + __expf(-(gi1 + hh1)));
    const float ng = tanhf(gi2 + rg * hh2);
    const float sn = (1.f - zg) * ng + zg * prev;
    const float mm = wsum64(sn) * (1.f / 64.f);
    const float df = sn - mm;
    const float vv = wsum64(df * df) * (1.f / 64.f);
    const float rr = 1.f / sqrtf(vv + LN_EPS);
    snsh[d] = sn;
    hsh[d] = df * rr * lnfw[d] + lnfb[d];
  }
  __syncthreads();                               // s6
  {
    const int j = tid & 127, ch2 = tid >> 7;
    float a = 0.f;
    for (int c = ch2 * 32; c < ch2 * 32 + 32; ++c) a += hsh[c] * w1[c * 128 + j];
    hid1[ch2][j] = a;
  }
  __syncthreads();                               // s7
  {
    float o = 0.f;
    for (int j2 = cq * 32; j2 < cq * 32 + 32; ++j2) {
      const float hv = fmaxf(hid1[0][j2] + hid1[1][j2] + b1[j2], 0.f);
      o += hv * w2[j2 * 64 + d];
    }
    pA[cq][d] = o;
  }
  __syncthreads();                               // s8
  float news = 0.f;
  if (cq == 0) {
    news = snsh[d] + b2[d] + pA[0][d] + pA[1][d] + pA[2][d] + pA[3][d];
    slots_out[bk_i * 64 + d] = news;
  }
  if (!do_prep) return;
  // ---- fused q-prep for next iteration ----
  if (cq == 0) {
    const float mm = wsum64(news) * (1.f / 64.f);
    const float df = news - mm;
    const float vv = wsum64(df * df) * (1.f / 64.f);
    const float rr = 1.f / sqrtf(vv + LN_EPS);
    xsh[d] = df * rr * lnsw[d] + lnsb[d];
  }
  __syncthreads();                               // s9
  {
    float qpt = 0.f;
    for (int c = c0; c < c0 + 16; ++c) qpt += xsh[c] * wq[c * 64 + d];
    pB[cq][d] = qpt;
  }
  __syncthreads();                               // s10
  if (cq == 0) qsh[d] = bq[d] + pB[0][d] + pB[1][d] + pB[2][d] + pB[3][d];
  __syncthreads();                               // s11
  {
    float qq = 0.f;
    for (int dd2 = c0; dd2 < c0 + 16; ++dd2) qq += wk[d * 64 + dd2] * qsh[dd2];
    pC[cq][d] = qq;
  }
  __syncthreads();                               // s12
  if (cq == 0) {
    const float qpv = pC[0][d] + pC[1][d] + pC[2][d] + pC[3][d];
    const float c0v = wsum64(qsh[d] * bkv[d]);
    const float qw = qpv * lniw[d] * SCALE;
    const float As = wsum64(qw);
    const float Bp = wsum64(qpv * lnib[d]);
    const float Bc = (Bp + c0v) * SCALE;
    float* rec = qprep + b * REC;
    rec[d * 8 + kk] = qw;
    if (d == 0) { rec[512 + kk] = As; rec[520 + kk] = Bc; }
  }
}

extern "C" void kernel_launch(void* const* d_in, const int* in_sizes, int n_in,
                              void* d_out, int out_size, void* d_ws, size_t ws_size,
                              hipStream_t stream) {
  const float* inp   = (const float*)d_in[0];
  const float* noise = (const float*)d_in[1];
  const float* mu    = (const float*)d_in[2];
  const float* sg    = (const float*)d_in[3];
  const float* lniw  = (const float*)d_in[4];
  const float* lnib  = (const float*)d_in[5];
  const float* lnsw  = (const float*)d_in[6];
  const float* lnsb  = (const float*)d_in[7];
  const float* lnfw  = (const float*)d_in[8];
  const float* lnfb  = (const float*)d_in[9];
  const float* wk    = (const float*)d_in[10];
  const float* bk    = (const float*)d_in[11];
  const float* wq    = (const float*)d_in[12];
  const float* bq    = (const float*)d_in[13];
  const float* wv    = (const float*)d_in[14];
  const float* bv    = (const float*)d_in[15];
  const float* wih   = (const float*)d_in[16];
  const float* bih   = (const float*)d_in[17];
  const float* whh   = (const float*)d_in[18];
  const float* bhh   = (const float*)d_in[19];
  const float* w1    = (const float*)d_in[20];
  const float* b1    = (const float*)d_in[21];
  const float* w2    = (const float*)d_in[22];
  const float* b2    = (const float*)d_in[23];
  float* ws = (float*)d_ws;
  float* slots = ws;                              // 32768
  float* qprep = ws + 32768;                      // 64*528 = 33792
  float* part  = ws + 32768 + 64 * REC;           // 1024*528 = 540672
  float* out   = (float*)d_out;
  init_slots<<<64, 512, 0, stream>>>(noise, mu, sg, slots);
  prep_q<<<B_ * K_, 64, 0, stream>>>(slots, lnsw, lnsb, wq, bq, wk, bk, lniw, lnib, qprep);
  for (int it = 0; it < 3; ++it) {
    attn_pass<<<B_ * CHUNKS, 256, 0, stream>>>(inp, qprep, part);
    slot_update<<<B_ * K_, 256, 0, stream>>>(
        part, slots, lniw, lnib, wv, bv, wih, bih, whh, bhh,
        lnfw, lnfb, w1, b1, w2, b2, lnsw, lnsb, wq, bq, wk, bk,
        (it == 2) ? out : slots, qprep, (it < 2) ? 1 : 0);
  }
}

// Round 9
// 485.292 us; speedup vs baseline: 1.3666x; 1.3666x over previous
//
#include <hip/hip_runtime.h>
#include <math.h>

#define B_ 64
#define N_ 16384
#define K_ 8
#define SCALE 0.125f          // 1/sqrt(64)
#define LN_EPS 1e-5f
#define CHUNKS 8
#define REC 528               // record: 512 Y + 8 S + 8 t1

__device__ __forceinline__ float wsum64(float v) {
#pragma unroll
  for (int m = 1; m < 64; m <<= 1) v += __shfl_xor(v, m);
  return v;
}

// async global->LDS, 16B/lane; LDS dest = wave-uniform base (+ lane*16 implicit)
__device__ __forceinline__ void dma16(const float* g, float* l) {
  __builtin_amdgcn_global_load_lds(
      (const __attribute__((address_space(1))) float*)g,
      (__attribute__((address_space(3))) float*)l, 16, 0, 0);
}

// slots = mu + sigma * noise   (32768 elems)
__global__ void init_slots(const float* __restrict__ noise, const float* __restrict__ mu,
                           const float* __restrict__ sg, float* __restrict__ slots) {
  int i = blockIdx.x * blockDim.x + threadIdx.x;
  int d = i & 63;
  slots[i] = mu[d] + sg[d] * noise[i];
}

// Per (b,kk): q = LN(slots; ln_slots)@wq + bq ; fold through wk and input-LN affine.
__global__ __launch_bounds__(64) void prep_q(
    const float* __restrict__ slots,
    const float* __restrict__ lnsw, const float* __restrict__ lnsb,
    const float* __restrict__ wq, const float* __restrict__ bq,
    const float* __restrict__ wk, const float* __restrict__ bk,
    const float* __restrict__ lniw, const float* __restrict__ lnib,
    float* __restrict__ qprep) {
  const int bk_i = blockIdx.x;            // b*8+kk
  const int b = bk_i >> 3, kk = bk_i & 7;
  const int d = threadIdx.x;
  __shared__ float xs[64], qsh[64], wkl[64 * 65];
  for (int i = 0; i < 64; ++i) wkl[i * 65 + d] = wk[i * 64 + d];
  float s = slots[bk_i * 64 + d];
  float m = wsum64(s) * (1.f / 64.f);
  float df = s - m;
  float var = wsum64(df * df) * (1.f / 64.f);
  float r = 1.f / sqrtf(var + LN_EPS);
  xs[d] = df * r * lnsw[d] + lnsb[d];
  __syncthreads();
  float q = bq[d];
  for (int c = 0; c < 64; ++c) q += xs[c] * wq[c * 64 + d];
  qsh[d] = q;
  __syncthreads();
  float qp = 0.f, c0 = 0.f;
  for (int dd = 0; dd < 64; ++dd) {
    float qd = qsh[dd];
    qp += wkl[d * 65 + dd] * qd;
    c0 += qd * bk[dd];
  }
  float qw = qp * lniw[d] * SCALE;
  float As = wsum64(qw);
  float Bp = wsum64(qp * lnib[d]);
  float Bc = (Bp + c0) * SCALE;
  float* rec = qprep + b * REC;
  rec[d * 8 + kk] = qw;                   // qwT[c][kk]
  if (d == 0) { rec[512 + kk] = As; rec[520 + kk] = Bc; }
}

// Streaming pass: grid = B*8 = 512 blocks x 256 threads, 2 blocks/CU (8 waves).
// Wave-private 64-row f32 microtile filled by global_load_lds with XOR-swizzled
// per-lane SOURCE (LDS dest linear => rule-21 safe); readers apply the same
// XOR => phase A (row-per-lane) and phase B (quad-per-lane) are conflict-free.
// No block barriers in the loop; per-tile vmcnt(0) stall hides under SIMD-mate.
__global__ __launch_bounds__(256, 2) void attn_pass(
    const float* __restrict__ inp, const float* __restrict__ qprep,
    float* __restrict__ part) {
  __shared__ __align__(16) float xls[4][64 * 64];   // 64 KB: wave-private tiles
  __shared__ __align__(16) float awl[4][64 * 12];   // 12 KB: a*r per row
  __shared__ float redST[64];
  const int tid = threadIdx.x;
  const int w = tid >> 6, lane = tid & 63;
  const int b = blockIdx.x >> 3, seg = blockIdx.x & 7;
  const float* __restrict__ qp = qprep + b * REC;   // wave-uniform -> s_load
  const float* srcw = inp + ((size_t)b * N_ + (size_t)(seg * 2048 + w * 512)) * 64;
  float As_[8], Bc_[8];
#pragma unroll
  for (int kq = 0; kq < 8; ++kq) { As_[kq] = qp[512 + kq]; Bc_[kq] = qp[520 + kq]; }
  float* __restrict__ xw = xls[w];
  float* __restrict__ aww = awl[w];
  const int g = lane >> 4, c = lane & 15;           // phase-B / DMA mapping
  float Y[8][4];
  float sS[8], sT[8];
#pragma unroll
  for (int kq = 0; kq < 8; ++kq) {
    sS[kq] = 0.f; sT[kq] = 0.f;
#pragma unroll
    for (int e = 0; e < 4; ++e) Y[kq][e] = 0.f;
  }
  // prologue: DMA tile 0 (16 insts x 1KB; lane (g,c): row 4i+g, src quad c^(row&7))
#pragma unroll
  for (int i = 0; i < 16; ++i) {
    const int r4 = i * 4 + g;
    const int sq = c ^ (r4 & 7);
    dma16(srcw + (size_t)r4 * 64 + sq * 4, xw + i * 256);
  }
  for (int t = 0; t < 8; ++t) {
    asm volatile("s_waitcnt vmcnt(0)" ::: "memory");
    __builtin_amdgcn_sched_barrier(0);
    // ---- phase A: row = lane; qw via scalar cache; swizzled row read ----
    float sum = 0.f, sq2 = 0.f;
    float l[8] = {0, 0, 0, 0, 0, 0, 0, 0};
#pragma unroll
    for (int j = 0; j < 16; ++j) {
      const int p = j ^ (lane & 7);
      const float4 xv = *reinterpret_cast<const float4*>(&xw[lane * 64 + p * 4]);
      const float xc[4] = {xv.x, xv.y, xv.z, xv.w};
#pragma unroll
      for (int e = 0; e < 4; ++e) {
        const int cc = j * 4 + e;
        const float v = xc[e];
        sum += v; sq2 += v * v;
#pragma unroll
        for (int kq = 0; kq < 8; ++kq) l[kq] += qp[cc * 8 + kq] * v;
      }
    }
    const float m = sum * (1.f / 64.f);
    const float var = sq2 * (1.f / 64.f) - m * m;
    const float rs = 1.f / sqrtf(var + LN_EPS);
    const float mr = m * rs;
    float lmax = -1e30f;
#pragma unroll
    for (int kq = 0; kq < 8; ++kq) {
      l[kq] = rs * l[kq] - mr * As_[kq] + Bc_[kq];
      lmax = fmaxf(lmax, l[kq]);
    }
    float es = 0.f;
#pragma unroll
    for (int kq = 0; kq < 8; ++kq) { l[kq] = __expf(l[kq] - lmax); es += l[kq]; }
    const float inv = 1.f / es;
#pragma unroll
    for (int kq = 0; kq < 8; ++kq) {
      const float a = l[kq] * inv;
      sS[kq] += a;
      sT[kq] += a * mr;
      l[kq] = a * rs;                    // a*r
    }
    *reinterpret_cast<float4*>(&aww[lane * 12])     = make_float4(l[0], l[1], l[2], l[3]);
    *reinterpret_cast<float4*>(&aww[lane * 12 + 4]) = make_float4(l[4], l[5], l[6], l[7]);
    // ---- phase B: lane (g,c): rows 4t+g, logical quad c (phys c^(row&7)) ----
#pragma unroll
    for (int t2 = 0; t2 < 16; ++t2) {
      const int row = 4 * t2 + g;
      const float4 a0 = *reinterpret_cast<const float4*>(&aww[row * 12]);
      const float4 a1 = *reinterpret_cast<const float4*>(&aww[row * 12 + 4]);
      const int p = c ^ (row & 7);
      const float4 xv = *reinterpret_cast<const float4*>(&xw[row * 64 + p * 4]);
      const float xc[4] = {xv.x, xv.y, xv.z, xv.w};
      const float aa[8] = {a0.x, a0.y, a0.z, a0.w, a1.x, a1.y, a1.z, a1.w};
#pragma unroll
      for (int kq = 0; kq < 8; ++kq)
#pragma unroll
        for (int e = 0; e < 4; ++e) Y[kq][e] += aa[kq] * xc[e];
    }
    // ---- issue DMA for tile t+1 (after all LDS reads of tile t retired) ----
    if (t < 7) {
      asm volatile("s_waitcnt lgkmcnt(0)" ::: "memory");
      __builtin_amdgcn_sched_barrier(0);
      const float* tb = srcw + (size_t)(t + 1) * 64 * 64;
#pragma unroll
      for (int i = 0; i < 16; ++i) {
        const int r4 = i * 4 + g;
        const int sq = c ^ (r4 & 7);
        dma16(tb + (size_t)r4 * 64 + sq * 4, xw + i * 256);
      }
    }
  }
  // ---- epilogue ----
#pragma unroll
  for (int kq = 0; kq < 8; ++kq) { sS[kq] = wsum64(sS[kq]); sT[kq] = wsum64(sT[kq]); }
  if (lane == 0) {
#pragma unroll
    for (int i = 0; i < 8; ++i) { redST[w * 16 + i] = sS[i]; redST[w * 16 + 8 + i] = sT[i]; }
  }
#pragma unroll
  for (int kq = 0; kq < 8; ++kq)
#pragma unroll
    for (int e = 0; e < 4; ++e) {
      Y[kq][e] += __shfl_xor(Y[kq][e], 16);
      Y[kq][e] += __shfl_xor(Y[kq][e], 32);
    }
  if (lane < 16) {     // lanes 0..15 hold quad c = lane
#pragma unroll
    for (int kq = 0; kq < 8; ++kq)
      *reinterpret_cast<float4*>(&aww[kq * 64 + lane * 4]) =
          make_float4(Y[kq][0], Y[kq][1], Y[kq][2], Y[kq][3]);
  }
  __syncthreads();
  float* dst = part + (size_t)blockIdx.x * REC;
  for (int o = tid; o < 512; o += 256)
    dst[o] = awl[0][o] + awl[1][o] + awl[2][o] + awl[3][o];
  if (tid < 16)
    dst[512 + tid] = redST[tid] + redST[16 + tid] + redST[32 + tid] + redST[48 + tid];
}

// Fused: partial-reduce -> updates -> GRU -> LN -> MLP -> new slots -> q-prep(next).
__global__ __launch_bounds__(256) void slot_update(
    const float* __restrict__ part, const float* slots_in,
    const float* __restrict__ lniw, const float* __restrict__ lnib,
    const float* __restrict__ wv, const float* __restrict__ bv,
    const float* __restrict__ wih, const float* __restrict__ bih,
    const float* __restrict__ whh, const float* __restrict__ bhh,
    const float* __restrict__ lnfw, const float* __restrict__ lnfb,
    const float* __restrict__ w1, const float* __restrict__ b1,
    const float* __restrict__ w2, const float* __restrict__ b2,
    const float* __restrict__ lnsw, const float* __restrict__ lnsb,
    const float* __restrict__ wq, const float* __restrict__ bq,
    const float* __restrict__ wk, const float* __restrict__ bkv,
    float* slots_out, float* __restrict__ qprep, const int do_prep) {
  const int bk_i = blockIdx.x, b = bk_i >> 3, kk = bk_i & 7;
  const int tid = threadIdx.x, cq = tid >> 6, d = tid & 63;
  const int c0 = cq * 16;
  __shared__ float pA[4][68], pB[4][68], pC[4][68], pD[4][68];
  __shared__ float xsh[64], psh[64], ush[64], hsh[64], snsh[64], qsh[64];
  __shared__ float hid1[2][132];
  const float* pb = part + (size_t)(b * CHUNKS) * REC;
  float S = 0.f, T1 = 0.f;
#pragma unroll
  for (int ch = 0; ch < CHUNKS; ++ch) {
    S += pb[ch * REC + 512 + kk];
    T1 += pb[ch * REC + 520 + kk];
  }
  {
    float y = 0.f;
#pragma unroll
    for (int cc = 0; cc < 2; ++cc)
      y += pb[(size_t)(cq * 2 + cc) * REC + kk * 64 + d];
    pA[cq][d] = y;
  }
  const float prev = slots_in[bk_i * 64 + d];
  if (cq == 0) psh[d] = prev;
  __syncthreads();                               // s1
  if (cq == 0) {
    const float Y = pA[0][d] + pA[1][d] + pA[2][d] + pA[3][d];
    xsh[d] = lniw[d] * (Y - T1) + lnib[d] * S;
  }
  __syncthreads();                               // s2
  {
    float up = 0.f, h0 = 0.f, h1 = 0.f, h2 = 0.f;
    for (int c = c0; c < c0 + 16; ++c) {
      const float xc = xsh[c], pc = psh[c];
      up += wv[c * 64 + d] * xc;
      h0 += pc * whh[c * 192 + d];
      h1 += pc * whh[c * 192 + 64 + d];
      h2 += pc * whh[c * 192 + 128 + d];
    }
    pA[cq][d] = up; pB[cq][d] = h0; pC[cq][d] = h1; pD[cq][d] = h2;
  }
  __syncthreads();                               // s3
  float hh0 = 0.f, hh1 = 0.f, hh2 = 0.f;
  if (cq == 0) {
    ush[d] = S * bv[d] + pA[0][d] + pA[1][d] + pA[2][d] + pA[3][d];
    hh0 = bhh[d] + pB[0][d] + pB[1][d] + pB[2][d] + pB[3][d];
    hh1 = bhh[64 + d] + pC[0][d] + pC[1][d] + pC[2][d] + pC[3][d];
    hh2 = bhh[128 + d] + pD[0][d] + pD[1][d] + pD[2][d] + pD[3][d];
  }
  __syncthreads();                               // s4
  {
    float g0 = 0.f, g1 = 0.f, g2 = 0.f;
    for (int c = c0; c < c0 + 16; ++c) {
      const float uc = ush[c];
      g0 += uc * wih[c * 192 + d];
      g1 += uc * wih[c * 192 + 64 + d];
      g2 += uc * wih[c * 192 + 128 + d];
    }
    pA[cq][d] = g0; pB[cq][d] = g1; pC[cq][d] = g2;
  }
  __syncthreads();                               // s5
  if (cq == 0) {
    const float gi0 = bih[d] + pA[0][d] + pA[1][d] + pA[2][d] + pA[3][d];
    const float gi1 = bih[64 + d] + pB[0][d] + pB[1][d] + pB[2][d] + pB[3][d];
    const float gi2 = bih[128 + d] + pC[0][d] + pC[1][d] + pC[2][d] + pC[3][d];
    const float rg = 1.f / (1.f + __expf(-(gi0 + hh0)));
    const float zg = 1.f / (1.f + __expf(-(gi1 + hh1)));
    const float ng = tanhf(gi2 + rg * hh2);
    const float sn = (1.f - zg) * ng + zg * prev;
    const float mm = wsum64(sn) * (1.f / 64.f);
    const float df = sn - mm;
    const float vv = wsum64(df * df) * (1.f / 64.f);
    const float rr = 1.f / sqrtf(vv + LN_EPS);
    snsh[d] = sn;
    hsh[d] = df * rr * lnfw[d] + lnfb[d];
  }
  __syncthreads();                               // s6
  {
    const int j = tid & 127, ch2 = tid >> 7;
    float a = 0.f;
    for (int c = ch2 * 32; c < ch2 * 32 + 32; ++c) a += hsh[c] * w1[c * 128 + j];
    hid1[ch2][j] = a;
  }
  __syncthreads();                               // s7
  {
    float o = 0.f;
    for (int j2 = cq * 32; j2 < cq * 32 + 32; ++j2) {
      const float hv = fmaxf(hid1[0][j2] + hid1[1][j2] + b1[j2], 0.f);
      o += hv * w2[j2 * 64 + d];
    }
    pA[cq][d] = o;
  }
  __syncthreads();                               // s8
  float news = 0.f;
  if (cq == 0) {
    news = snsh[d] + b2[d] + pA[0][d] + pA[1][d] + pA[2][d] + pA[3][d];
    slots_out[bk_i * 64 + d] = news;
  }
  if (!do_prep) return;
  // ---- fused q-prep for next iteration ----
  if (cq == 0) {
    const float mm = wsum64(news) * (1.f / 64.f);
    const float df = news - mm;
    const float vv = wsum64(df * df) * (1.f / 64.f);
    const float rr = 1.f / sqrtf(vv + LN_EPS);
    xsh[d] = df * rr * lnsw[d] + lnsb[d];
  }
  __syncthreads();                               // s9
  {
    float qpt = 0.f;
    for (int c = c0; c < c0 + 16; ++c) qpt += xsh[c] * wq[c * 64 + d];
    pB[cq][d] = qpt;
  }
  __syncthreads();                               // s10
  if (cq == 0) qsh[d] = bq[d] + pB[0][d] + pB[1][d] + pB[2][d] + pB[3][d];
  __syncthreads();                               // s11
  {
    float qq = 0.f;
    for (int dd2 = c0; dd2 < c0 + 16; ++dd2) qq += wk[d * 64 + dd2] * qsh[dd2];
    pC[cq][d] = qq;
  }
  __syncthreads();                               // s12
  if (cq == 0) {
    const float qpv = pC[0][d] + pC[1][d] + pC[2][d] + pC[3][d];
    const float c0v = wsum64(qsh[d] * bkv[d]);
    const float qw = qpv * lniw[d] * SCALE;
    const float As = wsum64(qw);
    const float Bp = wsum64(qpv * lnib[d]);
    const float Bc = (Bp + c0v) * SCALE;
    float* rec = qprep + b * REC;
    rec[d * 8 + kk] = qw;
    if (d == 0) { rec[512 + kk] = As; rec[520 + kk] = Bc; }
  }
}

extern "C" void kernel_launch(void* const* d_in, const int* in_sizes, int n_in,
                              void* d_out, int out_size, void* d_ws, size_t ws_size,
                              hipStream_t stream) {
  const float* inp   = (const float*)d_in[0];
  const float* noise = (const float*)d_in[1];
  const float* mu    = (const float*)d_in[2];
  const float* sg    = (const float*)d_in[3];
  const float* lniw  = (const float*)d_in[4];
  const float* lnib  = (const float*)d_in[5];
  const float* lnsw  = (const float*)d_in[6];
  const float* lnsb  = (const float*)d_in[7];
  const float* lnfw  = (const float*)d_in[8];
  const float* lnfb  = (const float*)d_in[9];
  const float* wk    = (const float*)d_in[10];
  const float* bk    = (const float*)d_in[11];
  const float* wq    = (const float*)d_in[12];
  const float* bq    = (const float*)d_in[13];
  const float* wv    = (const float*)d_in[14];
  const float* bv    = (const float*)d_in[15];
  const float* wih   = (const float*)d_in[16];
  const float* bih   = (const float*)d_in[17];
  const float* whh   = (const float*)d_in[18];
  const float* bhh   = (const float*)d_in[19];
  const float* w1    = (const float*)d_in[20];
  const float* b1    = (const float*)d_in[21];
  const float* w2    = (const float*)d_in[22];
  const float* b2    = (const float*)d_in[23];
  float* ws = (float*)d_ws;
  float* slots = ws;                              // 32768
  float* qprep = ws + 32768;                      // 64*528 = 33792
  float* part  = ws + 32768 + 64 * REC;           // 512*528 = 270336
  float* out   = (float*)d_out;
  init_slots<<<64, 512, 0, stream>>>(noise, mu, sg, slots);
  prep_q<<<B_ * K_, 64, 0, stream>>>(slots, lnsw, lnsb, wq, bq, wk, bk, lniw, lnib, qprep);
  for (int it = 0; it < 3; ++it) {
    attn_pass<<<B_ * CHUNKS, 256, 0, stream>>>(inp, qprep, part);
    slot_update<<<B_ * K_, 256, 0, stream>>>(
        part, slots, lniw, lnib, wv, bv, wih, bih, whh, bhh,
        lnfw, lnfb, w1, b1, w2, b2, lnsw, lnsb, wq, bq, wk, bk,
        (it == 2) ? out : slots, qprep, (it < 2) ? 1 : 0);
  }
}

// Round 10
// 437.097 us; speedup vs baseline: 1.5172x; 1.1103x over previous
//
#include <hip/hip_runtime.h>
#include <math.h>

#define B_ 64
#define N_ 16384
#define K_ 8
#define SCALE 0.125f          // 1/sqrt(64)
#define LN_EPS 1e-5f
#define CHUNKS 8
#define REC 528               // record: 512 Y + 8 S + 8 t1
#define NT 16                 // 32-row tiles per wave (512 rows)

__device__ __forceinline__ float wsum64(float v) {
#pragma unroll
  for (int m = 1; m < 64; m <<= 1) v += __shfl_xor(v, m);
  return v;
}

// async global->LDS, 16B/lane; LDS dest = wave-uniform base (+ lane*16 implicit)
__device__ __forceinline__ void dma16(const float* g, float* l) {
  __builtin_amdgcn_global_load_lds(
      (const __attribute__((address_space(1))) float*)g,
      (__attribute__((address_space(3))) float*)l, 16, 0, 0);
}

// slots = mu + sigma * noise   (32768 elems)
__global__ void init_slots(const float* __restrict__ noise, const float* __restrict__ mu,
                           const float* __restrict__ sg, float* __restrict__ slots) {
  int i = blockIdx.x * blockDim.x + threadIdx.x;
  int d = i & 63;
  slots[i] = mu[d] + sg[d] * noise[i];
}

// Per (b,kk): q = LN(slots; ln_slots)@wq + bq ; fold through wk and input-LN affine.
__global__ __launch_bounds__(64) void prep_q(
    const float* __restrict__ slots,
    const float* __restrict__ lnsw, const float* __restrict__ lnsb,
    const float* __restrict__ wq, const float* __restrict__ bq,
    const float* __restrict__ wk, const float* __restrict__ bk,
    const float* __restrict__ lniw, const float* __restrict__ lnib,
    float* __restrict__ qprep) {
  const int bk_i = blockIdx.x;            // b*8+kk
  const int b = bk_i >> 3, kk = bk_i & 7;
  const int d = threadIdx.x;
  __shared__ float xs[64], qsh[64], wkl[64 * 65];
  for (int i = 0; i < 64; ++i) wkl[i * 65 + d] = wk[i * 64 + d];
  float s = slots[bk_i * 64 + d];
  float m = wsum64(s) * (1.f / 64.f);
  float df = s - m;
  float var = wsum64(df * df) * (1.f / 64.f);
  float r = 1.f / sqrtf(var + LN_EPS);
  xs[d] = df * r * lnsw[d] + lnsb[d];
  __syncthreads();
  float q = bq[d];
  for (int c = 0; c < 64; ++c) q += xs[c] * wq[c * 64 + d];
  qsh[d] = q;
  __syncthreads();
  float qp = 0.f, c0 = 0.f;
  for (int dd = 0; dd < 64; ++dd) {
    float qd = qsh[dd];
    qp += wkl[d * 65 + dd] * qd;
    c0 += qd * bk[dd];
  }
  float qw = qp * lniw[d] * SCALE;
  float As = wsum64(qw);
  float Bp = wsum64(qp * lnib[d]);
  float Bc = (Bp + c0) * SCALE;
  float* rec = qprep + b * REC;
  rec[d * 8 + kk] = qw;                   // qwT[c][kk]
  if (d == 0) { rec[512 + kk] = As; rec[520 + kk] = Bc; }
}

// Streaming pass: grid = B*8 = 512 blocks x 256 threads, 2 blocks/CU (8 waves).
// Wave-private DOUBLE-BUFFERED 32-row tiles via global_load_lds with
// XOR-swizzled per-lane SOURCE (dest linear). vmcnt(8) keeps the next tile's
// 8 DMAs in flight across the whole compute phase -> >=8 outstanding always.
// Phase A: pair-per-row (shfl combine). Phase B: quad-per-lane. No block
// barriers in the loop.
__global__ __launch_bounds__(256, 2) void attn_pass(
    const float* __restrict__ inp, const float* __restrict__ qprep,
    float* __restrict__ part) {
  __shared__ __align__(16) float xls[4][2 * 32 * 64];  // 64 KB: 2 bufs/wave
  __shared__ __align__(16) float awl[4][32 * 20];      // 10 KB: a*r, stride 20
  __shared__ float redST[64];
  const int tid = threadIdx.x;
  const int w = tid >> 6, lane = tid & 63;
  const int b = blockIdx.x >> 3, seg = blockIdx.x & 7;
  const float* __restrict__ qp = qprep + b * REC;      // wave-uniform -> s_load
  const float* srcw = inp + ((size_t)b * N_ + (size_t)(seg * 2048 + w * 512)) * 64;
  float As_[8], Bc_[8];
#pragma unroll
  for (int kq = 0; kq < 8; ++kq) { As_[kq] = qp[512 + kq]; Bc_[kq] = qp[520 + kq]; }
  float* __restrict__ xw = xls[w];
  float* __restrict__ aww = awl[w];
  const int g = lane >> 4, c = lane & 15;   // DMA / phase-B mapping
  const int r = lane >> 1, h = lane & 1;    // phase-A pair mapping
  float Y[8][4];
  float sS[8], sT[8];
#pragma unroll
  for (int kq = 0; kq < 8; ++kq) {
    sS[kq] = 0.f; sT[kq] = 0.f;
#pragma unroll
    for (int e = 0; e < 4; ++e) Y[kq][e] = 0.f;
  }
  // prologue: DMA tiles 0 and 1 (8 insts x 1KB each; lane (g,c): row 4i+g,
  // source quad c^(row&7); dest linear => content phys q holds logical q^(row&7))
#pragma unroll
  for (int i = 0; i < 8; ++i) {
    const int r4 = i * 4 + g;
    dma16(srcw + (size_t)r4 * 64 + (c ^ (r4 & 7)) * 4, xw + i * 256);
  }
#pragma unroll
  for (int i = 0; i < 8; ++i) {
    const int r4 = i * 4 + g;
    dma16(srcw + (size_t)(32 + r4) * 64 + (c ^ (r4 & 7)) * 4, xw + 2048 + i * 256);
  }
  for (int t = 0; t < NT; ++t) {
    const int cur = t & 1;
    if (t < NT - 1) {
      asm volatile("s_waitcnt vmcnt(8)" ::: "memory");   // buf[cur] ready, next in flight
    } else {
      asm volatile("s_waitcnt vmcnt(0)" ::: "memory");
    }
    __builtin_amdgcn_sched_barrier(0);
    float* __restrict__ xb = xw + cur * 2048;
    // ---- phase A: pair (h) per row r; lane covers cols h*32..+31 ----
    float sum = 0.f, sq2 = 0.f;
    float l[8] = {0, 0, 0, 0, 0, 0, 0, 0};
#pragma unroll
    for (int jj = 0; jj < 8; ++jj) {
      const int q = h * 8 + jj;
      const int p = q ^ (r & 7);
      const float4 xv = *reinterpret_cast<const float4*>(&xb[r * 64 + p * 4]);
      const float xc[4] = {xv.x, xv.y, xv.z, xv.w};
#pragma unroll
      for (int e = 0; e < 4; ++e) {
        const int cc = q * 4 + e;
        const float v = xc[e];
        sum += v; sq2 += v * v;
#pragma unroll
        for (int kq = 0; kq < 8; ++kq) l[kq] += qp[cc * 8 + kq] * v;
      }
    }
#pragma unroll
    for (int kq = 0; kq < 8; ++kq) l[kq] += __shfl_xor(l[kq], 1);
    sum += __shfl_xor(sum, 1);
    sq2 += __shfl_xor(sq2, 1);
    const float m = sum * (1.f / 64.f);
    const float var = sq2 * (1.f / 64.f) - m * m;
    const float rs = 1.f / sqrtf(var + LN_EPS);
    const float mr = m * rs;
    float lmax = -1e30f;
#pragma unroll
    for (int kq = 0; kq < 8; ++kq) {
      l[kq] = rs * l[kq] - mr * As_[kq] + Bc_[kq];
      lmax = fmaxf(lmax, l[kq]);
    }
    float es = 0.f;
#pragma unroll
    for (int kq = 0; kq < 8; ++kq) { l[kq] = __expf(l[kq] - lmax); es += l[kq]; }
    const float inv = 1.f / es;
#pragma unroll
    for (int kq = 0; kq < 8; ++kq) {
      const float a = l[kq] * inv;
      sS[kq] += a;                       // pair-redundant -> 0.5x at epilogue
      sT[kq] += a * mr;
      l[kq] = a * rs;                    // a*r
    }
    if (h == 0) {                        // stride-20 float4s tile all 32 banks
      *reinterpret_cast<float4*>(&aww[r * 20])     = make_float4(l[0], l[1], l[2], l[3]);
      *reinterpret_cast<float4*>(&aww[r * 20 + 4]) = make_float4(l[4], l[5], l[6], l[7]);
    }
    // ---- phase B: lane (g,c): rows 4t2+g, logical quad c (phys c^(row&7)) ----
#pragma unroll
    for (int t2 = 0; t2 < 8; ++t2) {
      const int row = 4 * t2 + g;
      const float4 a0 = *reinterpret_cast<const float4*>(&aww[row * 20]);
      const float4 a1 = *reinterpret_cast<const float4*>(&aww[row * 20 + 4]);
      const int p = c ^ (row & 7);
      const float4 xv = *reinterpret_cast<const float4*>(&xb[row * 64 + p * 4]);
      const float xc[4] = {xv.x, xv.y, xv.z, xv.w};
      const float aa[8] = {a0.x, a0.y, a0.z, a0.w, a1.x, a1.y, a1.z, a1.w};
#pragma unroll
      for (int kq = 0; kq < 8; ++kq)
#pragma unroll
        for (int e = 0; e < 4; ++e) Y[kq][e] += aa[kq] * xc[e];
    }
    // ---- issue DMA for tile t+2 into buf[cur] (reads of buf[cur] retired) ----
    if (t + 2 < NT) {
      asm volatile("s_waitcnt lgkmcnt(0)" ::: "memory");
      __builtin_amdgcn_sched_barrier(0);
      const float* tb = srcw + (size_t)(t + 2) * 32 * 64;
#pragma unroll
      for (int i = 0; i < 8; ++i) {
        const int r4 = i * 4 + g;
        dma16(tb + (size_t)r4 * 64 + (c ^ (r4 & 7)) * 4, xb + i * 256);
      }
    }
  }
  // ---- epilogue ----
#pragma unroll
  for (int kq = 0; kq < 8; ++kq) { sS[kq] = wsum64(sS[kq]); sT[kq] = wsum64(sT[kq]); }
  if (lane == 0) {
#pragma unroll
    for (int i = 0; i < 8; ++i) { redST[w * 16 + i] = sS[i]; redST[w * 16 + 8 + i] = sT[i]; }
  }
#pragma unroll
  for (int kq = 0; kq < 8; ++kq)
#pragma unroll
    for (int e = 0; e < 4; ++e) {
      Y[kq][e] += __shfl_xor(Y[kq][e], 16);
      Y[kq][e] += __shfl_xor(Y[kq][e], 32);
    }
  if (lane < 16) {     // lanes 0..15 hold quad c = lane
#pragma unroll
    for (int kq = 0; kq < 8; ++kq)
      *reinterpret_cast<float4*>(&aww[kq * 64 + lane * 4]) =
          make_float4(Y[kq][0], Y[kq][1], Y[kq][2], Y[kq][3]);
  }
  __syncthreads();
  float* dst = part + (size_t)blockIdx.x * REC;
  for (int o = tid; o < 512; o += 256)
    dst[o] = awl[0][o] + awl[1][o] + awl[2][o] + awl[3][o];
  if (tid < 16)
    dst[512 + tid] = 0.5f * (redST[tid] + redST[16 + tid] + redST[32 + tid] + redST[48 + tid]);
}

// Fused: partial-reduce -> updates -> GRU -> LN -> MLP -> new slots -> q-prep(next).
__global__ __launch_bounds__(256) void slot_update(
    const float* __restrict__ part, const float* slots_in,
    const float* __restrict__ lniw, const float* __restrict__ lnib,
    const float* __restrict__ wv, const float* __restrict__ bv,
    const float* __restrict__ wih, const float* __restrict__ bih,
    const float* __restrict__ whh, const float* __restrict__ bhh,
    const float* __restrict__ lnfw, const float* __restrict__ lnfb,
    const float* __restrict__ w1, const float* __restrict__ b1,
    const float* __restrict__ w2, const float* __restrict__ b2,
    const float* __restrict__ lnsw, const float* __restrict__ lnsb,
    const float* __restrict__ wq, const float* __restrict__ bq,
    const float* __restrict__ wk, const float* __restrict__ bkv,
    float* slots_out, float* __restrict__ qprep, const int do_prep) {
  const int bk_i = blockIdx.x, b = bk_i >> 3, kk = bk_i & 7;
  const int tid = threadIdx.x, cq = tid >> 6, d = tid & 63;
  const int c0 = cq * 16;
  __shared__ float pA[4][68], pB[4][68], pC[4][68], pD[4][68];
  __shared__ float xsh[64], psh[64], ush[64], hsh[64], snsh[64], qsh[64];
  __shared__ float hid1[2][132];
  const float* pb = part + (size_t)(b * CHUNKS) * REC;
  float S = 0.f, T1 = 0.f;
#pragma unroll
  for (int ch = 0; ch < CHUNKS; ++ch) {
    S += pb[ch * REC + 512 + kk];
    T1 += pb[ch * REC + 520 + kk];
  }
  {
    float y = 0.f;
#pragma unroll
    for (int cc = 0; cc < 2; ++cc)
      y += pb[(size_t)(cq * 2 + cc) * REC + kk * 64 + d];
    pA[cq][d] = y;
  }
  const float prev = slots_in[bk_i * 64 + d];
  if (cq == 0) psh[d] = prev;
  __syncthreads();                               // s1
  if (cq == 0) {
    const float Y = pA[0][d] + pA[1][d] + pA[2][d] + pA[3][d];
    xsh[d] = lniw[d] * (Y - T1) + lnib[d] * S;
  }
  __syncthreads();                               // s2
  {
    float up = 0.f, h0 = 0.f, h1 = 0.f, h2 = 0.f;
    for (int c = c0; c < c0 + 16; ++c) {
      const float xc = xsh[c], pc = psh[c];
      up += wv[c * 64 + d] * xc;
      h0 += pc * whh[c * 192 + d];
      h1 += pc * whh[c * 192 + 64 + d];
      h2 += pc * whh[c * 192 + 128 + d];
    }
    pA[cq][d] = up; pB[cq][d] = h0; pC[cq][d] = h1; pD[cq][d] = h2;
  }
  __syncthreads();                               // s3
  float hh0 = 0.f, hh1 = 0.f, hh2 = 0.f;
  if (cq == 0) {
    ush[d] = S * bv[d] + pA[0][d] + pA[1][d] + pA[2][d] + pA[3][d];
    hh0 = bhh[d] + pB[0][d] + pB[1][d] + pB[2][d] + pB[3][d];
    hh1 = bhh[64 + d] + pC[0][d] + pC[1][d] + pC[2][d] + pC[3][d];
    hh2 = bhh[128 + d] + pD[0][d] + pD[1][d] + pD[2][d] + pD[3][d];
  }
  __syncthreads();                               // s4
  {
    float g0 = 0.f, g1 = 0.f, g2 = 0.f;
    for (int c = c0; c < c0 + 16; ++c) {
      const float uc = ush[c];
      g0 += uc * wih[c * 192 + d];
      g1 += uc * wih[c * 192 + 64 + d];
      g2 += uc * wih[c * 192 + 128 + d];
    }
    pA[cq][d] = g0; pB[cq][d] = g1; pC[cq][d] = g2;
  }
  __syncthreads();                               // s5
  if (cq == 0) {
    const float gi0 = bih[d] + pA[0][d] + pA[1][d] + pA[2][d] + pA[3][d];
    const float gi1 = bih[64 + d] + pB[0][d] + pB[1][d] + pB[2][d] + pB[3][d];
    const float gi2 = bih[128 + d] + pC[0][d] + pC[1][d] + pC[2][d] + pC[3][d];
    const float rg = 1.f / (1.f + __expf(-(gi0 + hh0)));
    const float zg = 1.f / (1.f + __expf(-(gi1 + hh1)));
    const float ng = tanhf(gi2 + rg * hh2);
    const float sn = (1.f - zg) * ng + zg * prev;
    const float mm = wsum64(sn) * (1.f / 64.f);
    const float df = sn - mm;
    const float vv = wsum64(df * df) * (1.f / 64.f);
    const float rr = 1.f / sqrtf(vv + LN_EPS);
    snsh[d] = sn;
    hsh[d] = df * rr * lnfw[d] + lnfb[d];
  }
  __syncthreads();                               // s6
  {
    const int j = tid & 127, ch2 = tid >> 7;
    float a = 0.f;
    for (int c = ch2 * 32; c < ch2 * 32 + 32; ++c) a += hsh[c] * w1[c * 128 + j];
    hid1[ch2][j] = a;
  }
  __syncthreads();                               // s7
  {
    float o = 0.f;
    for (int j2 = cq * 32; j2 < cq * 32 + 32; ++j2) {
      const float hv = fmaxf(hid1[0][j2] + hid1[1][j2] + b1[j2], 0.f);
      o += hv * w2[j2 * 64 + d];
    }
    pA[cq][d] = o;
  }
  __syncthreads();                               // s8
  float news = 0.f;
  if (cq == 0) {
    news = snsh[d] + b2[d] + pA[0][d] + pA[1][d] + pA[2][d] + pA[3][d];
    slots_out[bk_i * 64 + d] = news;
  }
  if (!do_prep) return;
  // ---- fused q-prep for next iteration ----
  if (cq == 0) {
    const float mm = wsum64(news) * (1.f / 64.f);
    const float df = news - mm;
    const float vv = wsum64(df * df) * (1.f / 64.f);
    const float rr = 1.f / sqrtf(vv + LN_EPS);
    xsh[d] = df * rr * lnsw[d] + lnsb[d];
  }
  __syncthreads();                               // s9
  {
    float qpt = 0.f;
    for (int c = c0; c < c0 + 16; ++c) qpt += xsh[c] * wq[c * 64 + d];
    pB[cq][d] = qpt;
  }
  __syncthreads();                               // s10
  if (cq == 0) qsh[d] = bq[d] + pB[0][d] + pB[1][d] + pB[2][d] + pB[3][d];
  __syncthreads();                               // s11
  {
    float qq = 0.f;
    for (int dd2 = c0; dd2 < c0 + 16; ++dd2) qq += wk[d * 64 + dd2] * qsh[dd2];
    pC[cq][d] = qq;
  }
  __syncthreads();                               // s12
  if (cq == 0) {
    const float qpv = pC[0][d] + pC[1][d] + pC[2][d] + pC[3][d];
    const float c0v = wsum64(qsh[d] * bkv[d]);
    const float qw = qpv * lniw[d] * SCALE;
    const float As = wsum64(qw);
    const float Bp = wsum64(qpv * lnib[d]);
    const float Bc = (Bp + c0v) * SCALE;
    float* rec = qprep + b * REC;
    rec[d * 8 + kk] = qw;
    if (d == 0) { rec[512 + kk] = As; rec[520 + kk] = Bc; }
  }
}

extern "C" void kernel_launch(void* const* d_in, const int* in_sizes, int n_in,
                              void* d_out, int out_size, void* d_ws, size_t ws_size,
                              hipStream_t stream) {
  const float* inp   = (const float*)d_in[0];
  const float* noise = (const float*)d_in[1];
  const float* mu    = (const float*)d_in[2];
  const float* sg    = (const float*)d_in[3];
  const float* lniw  = (const float*)d_in[4];
  const float* lnib  = (const float*)d_in[5];
  const float* lnsw  = (const float*)d_in[6];
  const float* lnsb  = (const float*)d_in[7];
  const float* lnfw  = (const float*)d_in[8];
  const float* lnfb  = (const float*)d_in[9];
  const float* wk    = (const float*)d_in[10];
  const float* bk    = (const float*)d_in[11];
  const float* wq    = (const float*)d_in[12];
  const float* bq    = (const float*)d_in[13];
  const float* wv    = (const float*)d_in[14];
  const float* bv    = (const float*)d_in[15];
  const float* wih   = (const float*)d_in[16];
  const float* bih   = (const float*)d_in[17];
  const float* whh   = (const float*)d_in[18];
  const float* bhh   = (const float*)d_in[19];
  const float* w1    = (const float*)d_in[20];
  const float* b1    = (const float*)d_in[21];
  const float* w2    = (const float*)d_in[22];
  const float* b2    = (const float*)d_in[23];
  float* ws = (float*)d_ws;
  float* slots = ws;                              // 32768
  float* qprep = ws + 32768;                      // 64*528 = 33792
  float* part  = ws + 32768 + 64 * REC;           // 512*528 = 270336
  float* out   = (float*)d_out;
  init_slots<<<64, 512, 0, stream>>>(noise, mu, sg, slots);
  prep_q<<<B_ * K_, 64, 0, stream>>>(slots, lnsw, lnsb, wq, bq, wk, bk, lniw, lnib, qprep);
  for (int it = 0; it < 3; ++it) {
    attn_pass<<<B_ * CHUNKS, 256, 0, stream>>>(inp, qprep, part);
    slot_update<<<B_ * K_, 256, 0, stream>>>(
        part, slots, lniw, lnib, wv, bv, wih, bih, whh, bhh,
        lnfw, lnfb, w1, b1, w2, b2, lnsw, lnsb, wq, bq, wk, bk,
        (it == 2) ? out : slots, qprep, (it < 2) ? 1 : 0);
  }
}